// Round 2
// baseline (687.933 us; speedup 1.0000x reference)
//
#include <hip/hip_runtime.h>
#include <math.h>

#define NEARZERO 1e-5f
#define LENF 15

// ---- LDS ring geometry -----------------------------------------------------
// 32 n-chains per block, 2 chains per lane (chain A: nl 0..15, chain B: 16..31).
// Each step-slot: 8KB param slab (praw[t, n0:n0+32, 0:16, 0:4]) staged as
// 8 x 1KB global_load_lds(width=16) chunks with 16B inter-chunk pad, plus a
// 384B forcing slab (x[t, n0:n0+32, 0:3]) staged with one width=16 load (24 lanes).
//
// Bank-conflict fix: within each 1KB chunk (4 n values, q = nl&3), 16B beat
// (q, i) is stored at beat index 16*q + (i ^ 2q) instead of 16*q + i. This is
// achieved by PRE-SWIZZLING the per-lane GLOBAL source address at stage time
// (perm(l) = l ^ ((l>>3)&6), an involution; LDS dest stays linear as
// global_load_lds requires). Reads use precomputed per-lane address registers
// (4 param regs + 1 forcing reg per chain), with slot encoded in the ds offset
// immediate -> zero per-read address VALU. Read banks: 2 lanes/bank (free).
#define KB 2                                   // steps per batch
#define NCHUNK 8
#define CHUNK_STRIDE (1024 + 16)               // 1040 B
#define SLOT_PARAM (NCHUNK * CHUNK_STRIDE)     // 8320 B
#define SLOT_BYTES (SLOT_PARAM + 384)          // 8704 B (16B-aligned)
#define BUF_BYTES (KB * SLOT_BYTES)            // 17408 B
#define LDS_BYTES (2 * BUF_BYTES)              // 34816 B

// s_waitcnt immediates (gfx9: vmcnt[3:0]|[15:14], exp[6:4], lgkm[11:8])
#define WAIT_VMCNT_18 0x4F72                   // vmcnt(18)  (prologue: loads only)
#define WAIT_VMCNT_20 0x4F74                   // vmcnt(20)  (loop: 18 loads + 2 stores)
#define WAIT_LGKM_0   0xC07F                   // lgkmcnt(0)

#define GPTR(p) ((const __attribute__((address_space(1))) void*)(p))
#define LPTR(p) ((__attribute__((address_space(3))) void*)(p))

// DPP quad_perm swaps within each quad of lanes (VALU, no LDS).
__device__ __forceinline__ float qswap1(float v) {
    return __int_as_float(__builtin_amdgcn_update_dpp(
        0, __float_as_int(v), 0xB1 /* quad_perm(1,0,3,2) */, 0xF, 0xF, true));
}
__device__ __forceinline__ float qswap2(float v) {
    return __int_as_float(__builtin_amdgcn_update_dpp(
        0, __float_as_int(v), 0x4E /* quad_perm(2,3,0,1) */, 0xF, 0xF, true));
}

// Fast x^y for x > 0 via v_log_f32/v_exp_f32 (both call sites clip to [0,1]
// and have provably positive arguments).
__device__ __forceinline__ float powpos(float x, float y) {
    return __builtin_amdgcn_exp2f(y * __builtin_amdgcn_logf(x));
}
// Raw v_rcp_f32 (1 ulp) instead of OCML correctly-rounded reciprocal.
__device__ __forceinline__ float rcpf(float x) { return __builtin_amdgcn_rcpf(x); }

// Stage one batch (KB steps). 9 vmem instructions per step = 18 per batch,
// ALWAYS issued (t clamped) so the vmcnt arithmetic stays exact.
__device__ __forceinline__ void stage_batch(const char* __restrict__ praw_b,
                                            const char* __restrict__ x_b,
                                            char* smem, int buf, int t0,
                                            int T, int N, int n0, int lane,
                                            int perm16)
{
    char* bufp = smem + buf * BUF_BYTES;
    for (int s = 0; s < KB; ++s) {
        int ts = t0 + s;
        if (ts > T - 1) ts = T - 1;
        const char* gp = praw_b + (size_t)ts * ((size_t)N * 256) + (size_t)n0 * 256;
        char* sp = bufp + s * SLOT_BYTES;
#pragma unroll
        for (int c = 0; c < NCHUNK; ++c) {
            __builtin_amdgcn_global_load_lds(GPTR(gp + c * 1024 + perm16),
                                             LPTR(sp + c * CHUNK_STRIDE),
                                             16, 0, 0);
        }
        const char* xg = x_b + (size_t)ts * ((size_t)N * 12) + (size_t)n0 * 12;
        if (lane < 24) {
            __builtin_amdgcn_global_load_lds(GPTR(xg + lane * 16),
                                             LPTR(sp + SLOT_PARAM),
                                             16, 0, 0);
        }
    }
}

__device__ __forceinline__ float dostep(const float* __restrict__ pr, // 14 regs
                                        float P, float Ta, float PET,
                                        float& SNOWPACK, float& MELTWATER,
                                        float& SM, float& SUZ, float& SLZ)
{
    // TT is the only jump-discontinuous parameter (Ta >= TT): compute with
    // unfused mul+add to bit-match numpy's lo + raw*(hi-lo).
    const float BETA   = fmaf(pr[0],  5.0f,   1.0f);
    const float FC     = fmaf(pr[1],  950.0f, 50.0f);
    const float K0     = fmaf(pr[2],  0.85f,  0.05f);
    const float K1     = fmaf(pr[3],  0.49f,  0.01f);
    const float K2     = fmaf(pr[4],  0.199f, 0.001f);
    const float LP     = fmaf(pr[5],  0.8f,   0.2f);
    const float PERC   = pr[6] * 10.0f;
    const float UZL    = pr[7] * 100.0f;
    const float TT     = __fadd_rn(-2.5f, __fmul_rn(pr[8], 5.0f));
    const float CFMAX  = fmaf(pr[9],  9.5f,   0.5f);
    const float CFR    = pr[10] * 0.1f;
    const float CWH    = pr[11] * 0.2f;
    const float BETAET = fmaf(pr[12], 4.7f,   0.3f);
    const float C      = pr[13];

    const bool  wet  = (Ta >= TT);
    const float RAIN = wet ? P : 0.0f;
    const float SNOW = wet ? 0.0f : P;

    SNOWPACK += SNOW;
    const float melt = fminf(fmaxf(CFMAX * (Ta - TT), 0.0f), SNOWPACK);
    MELTWATER += melt;
    SNOWPACK = fmaxf(SNOWPACK - melt, NEARZERO);
    const float refreeze = fminf(fmaxf(CFR * CFMAX * (TT - Ta), 0.0f), MELTWATER);
    SNOWPACK += refreeze;
    MELTWATER = fmaxf(MELTWATER - refreeze, NEARZERO);
    const float tosoil = fmaxf(MELTWATER - CWH * SNOWPACK, 0.0f);
    MELTWATER = fmaxf(MELTWATER - tosoil, NEARZERO);

    const float rFC = rcpf(FC);
    float soil_wet = powpos(SM * rFC, BETA);
    soil_wet = fminf(fmaxf(soil_wet, 0.0f), 1.0f);
    const float recharge = (RAIN + tosoil) * soil_wet;
    SM = SM + RAIN + tosoil - recharge;
    const float excess = fmaxf(SM - FC, 0.0f);
    SM = fmaxf(SM - excess, NEARZERO);

    float evapfactor = powpos(SM * rcpf(LP * FC), BETAET);
    evapfactor = fminf(fmaxf(evapfactor, 0.0f), 1.0f);
    const float ETact = fminf(SM, PET * evapfactor);
    SM = fmaxf(SM - ETact, NEARZERO);

    const float capillary = fminf(SLZ, C * SLZ * (1.0f - fminf(SM * rFC, 1.0f)));
    SM += capillary;
    SLZ = fmaxf(SLZ - capillary, NEARZERO);

    SUZ = SUZ + recharge + excess;
    const float PERCa = fminf(SUZ, PERC);
    SUZ -= PERCa;
    const float Q0 = K0 * fmaxf(SUZ - UZL, 0.0f);
    SUZ -= Q0;
    const float Q1 = K1 * SUZ;
    SUZ -= Q1;
    SLZ += PERCa;
    const float Q2 = K2 * SLZ;
    SLZ -= Q2;
    return Q0 + Q1 + Q2;
}

// Log-domain gamma unit hydrograph: w_k = exp2(c + (aa-1)*log2(t_k) - t_k/th*log2e),
// normalized. Avoids 15 OCML powf calls per chain.
__device__ __forceinline__ void make_uh(float craw0, float craw1, float* UH)
{
    const float a  = craw0 * 2.9f;
    const float b  = craw1 * 6.5f;
    const float aa = fmaxf(a, 0.0f) + 0.1f;
    const float th = fmaxf(b, 0.0f) + 0.5f;
    const float L2E = 1.4426950408889634f;
    const float c   = -lgammaf(aa) * L2E - aa * __builtin_amdgcn_logf(th);
    const float rthL = rcpf(th) * L2E;
    float wsum = 0.0f;
#pragma unroll
    for (int k = 0; k < LENF; ++k) {
        const float tt   = (float)k + 0.5f;
        const float l2tt = __builtin_log2f((float)k + 0.5f);   // constant-folded
        const float l2w  = fmaf(aa - 1.0f, l2tt, c) - tt * rthL;
        UH[k] = __builtin_amdgcn_exp2f(l2w);
        wsum += UH[k];
    }
    const float rs = rcpf(wsum);
#pragma unroll
    for (int k = 0; k < LENF; ++k) UH[k] *= rs;
}

__global__ void __launch_bounds__(64, 1)
hbv_kernel(const float* __restrict__ x,      // (T, N, 3)
           const float* __restrict__ praw,   // (T, N, 16, 4)
           const float* __restrict__ conv,   // (N, 2)
           float* __restrict__ out,          // (T, N)
           int T, int N)
{
    __shared__ __align__(16) char smem[LDS_BYTES];

    const int lane = threadIdx.x;
    int n0 = blockIdx.x * 32;                // 32 n-chains per block
    if (n0 > N - 32) n0 = N - 32;            // safety clamp (duplicate writes benign)
    const int nlA = lane >> 2;               // 0..15
    const int m   = lane & 3;                // ensemble member
    const int nA  = n0 + nlA;
    const int nB  = nA + 16;
    // Stage-side source swizzle: beat l reads global beat l ^ ((l>>3)&6).
    const int perm16 = (lane ^ ((lane >> 3) & 6)) << 4;

    // --- Per-chain LDS read address registers (absolute, buf0/slot0) ---------
    // Param i (bits b3 b2 b1 b0) lives at col + 128*b3 + 64*(b2^q1) + 32*(b1^q0)
    // + 16*b0 bytes, col = a*CHUNK_STRIDE + q*256 + m*4 (a = nl>>2, q = nl&3).
    const int qA  = nlA & 3;
    const int q0A = qA & 1, q1A = (qA >> 1) & 1;
    const int colA = (nlA >> 2) * CHUNK_STRIDE + qA * 256 + m * 4;
    const int colB = ((nlA + 16) >> 2) * CHUNK_STRIDE + qA * 256 + m * 4;
    char *pA[4], *pB[4], *pfA, *pfB;
#pragma unroll
    for (int j = 0; j < 4; ++j) {
        const int d = 64 * (((j >> 1) & 1) ^ q1A) + 32 * ((j & 1) ^ q0A);
        pA[j] = smem + colA + d;
        pB[j] = smem + colB + d;
    }
    pfA = smem + SLOT_PARAM + 12 * nlA;
    pfB = smem + SLOT_PARAM + 12 * (nlA + 16);

    // --- Unit hydrographs (identical across the 4 lanes of a quad) ----------
    float UHA[LENF], UHB[LENF];
    make_uh(conv[2 * nA], conv[2 * nA + 1], UHA);
    make_uh(conv[2 * nB], conv[2 * nB + 1], UHB);

    float accA[LENF - 1], accB[LENF - 1];
#pragma unroll
    for (int k = 0; k < LENF - 1; ++k) { accA[k] = 0.0f; accB[k] = 0.0f; }

    float SA0 = 0.001f, SA1 = 0.001f, SA2 = 0.001f, SA3 = 0.001f, SA4 = 0.001f;
    float SB0 = 0.001f, SB1 = 0.001f, SB2 = 0.001f, SB3 = 0.001f, SB4 = 0.001f;

    const char* praw_b = (const char*)praw;
    const char* x_b    = (const char*)x;

    // Prologue: two batches in flight.
    stage_batch(praw_b, x_b, smem, 0, 0,  T, N, n0, lane, perm16);
    stage_batch(praw_b, x_b, smem, 1, KB, T, N, n0, lane, perm16);

    float p1A[14], f1A[3], p1B[14], f1B[3];  // R1 slab
    float p2A[14], f2A[3], p2B[14], f2B[3];  // R2 slab

#define LOADSLOT(P_A, F_A, P_B, F_B, SOFS)                                    \
    {                                                                         \
        _Pragma("unroll")                                                     \
        for (int i = 0; i < 14; ++i) {                                        \
            const int j = 2 * ((i >> 2) & 1) + ((i >> 1) & 1);                \
            const int o = (SOFS) + 128 * (i >> 3) + 16 * (i & 1);             \
            P_A[i] = *(const float*)(pA[j] + o);                              \
            P_B[i] = *(const float*)(pB[j] + o);                              \
        }                                                                     \
        _Pragma("unroll")                                                     \
        for (int k = 0; k < 3; ++k) {                                         \
            F_A[k] = *(const float*)(pfA + (SOFS) + 4 * k);                   \
            F_B[k] = *(const float*)(pfB + (SOFS) + 4 * k);                   \
        }                                                                     \
    }

#define STEPT(P_A, F_A, P_B, F_B, TIDX)                                       \
    {                                                                         \
        float vA = dostep(P_A, F_A[0], F_A[1], F_A[2], SA0, SA1, SA2, SA3, SA4); \
        float vB = dostep(P_B, F_B[0], F_B[1], F_B[2], SB0, SB1, SB2, SB3, SB4); \
        vA += qswap1(vA);  vB += qswap1(vB);                                  \
        vA += qswap2(vA);  vB += qswap2(vB);                                  \
        const float qqA = vA * 0.25f, qqB = vB * 0.25f;                       \
        const float eA = fmaf(UHA[0], qqA, accA[0]);                          \
        const float eB = fmaf(UHB[0], qqB, accB[0]);                          \
        _Pragma("unroll")                                                     \
        for (int k = 0; k < LENF - 2; ++k) {                                  \
            accA[k] = fmaf(UHA[k + 1], qqA, accA[k + 1]);                     \
            accB[k] = fmaf(UHB[k + 1], qqB, accB[k + 1]);                     \
        }                                                                     \
        accA[LENF - 2] = UHA[LENF - 1] * qqA;                                 \
        accB[LENF - 2] = UHB[LENF - 1] * qqB;                                 \
        if (m == 0) {                                                         \
            out[(size_t)(TIDX) * N + nA] = eA;                                \
            out[(size_t)(TIDX) * N + nB] = eB;                                \
        }                                                                     \
    }

    __builtin_amdgcn_s_waitcnt(WAIT_VMCNT_18);    // batch 0 resident
    __builtin_amdgcn_sched_barrier(0);
    LOADSLOT(p1A, f1A, p1B, f1B, 0);              // R1 <- b0.s0

    int dl = BUF_BYTES;                            // ping-pong pointer delta
    int t = 0;
    const int nb = T / KB;                         // 182 full batches
    for (int bb = 0; bb < nb; ++bb) {
        // R2 <- cur.s1 (latency hidden under STEPT(R1))
        LOADSLOT(p2A, f2A, p2B, f2B, SLOT_BYTES);
        STEPT(p1A, f1A, p1B, f1B, t);
        // All ds_reads from cur are in regs; safe to overwrite via DMA.
        __builtin_amdgcn_s_waitcnt(WAIT_LGKM_0);
        __builtin_amdgcn_sched_barrier(0);
        stage_batch(praw_b, x_b, smem, bb & 1, (bb + 2) * KB, T, N, n0, lane, perm16);
        // Batch bb+1 resident: <=18 newest loads (bb+2) + 2 newest stores allowed.
        __builtin_amdgcn_s_waitcnt(WAIT_VMCNT_20);
        __builtin_amdgcn_sched_barrier(0);
#pragma unroll
        for (int j = 0; j < 4; ++j) { pA[j] += dl; pB[j] += dl; }
        pfA += dl; pfB += dl; dl = -dl;
        // R1 <- next batch s0 (other buffer; latency hidden under STEPT(R2))
        LOADSLOT(p1A, f1A, p1B, f1B, 0);
        STEPT(p2A, f2A, p2B, f2B, t + 1);
        t += KB;
    }

    // Tail: T odd -> exactly 1 step, R1 already loaded.
    if (t < T) {
        STEPT(p1A, f1A, p1B, f1B, t);
    }
#undef LOADSLOT
#undef STEPT
}

extern "C" void kernel_launch(void* const* d_in, const int* in_sizes, int n_in,
                              void* d_out, int out_size, void* d_ws, size_t ws_size,
                              hipStream_t stream)
{
    const float* x    = (const float*)d_in[0];  // (T, N, 3)
    const float* praw = (const float*)d_in[1];  // (T, N, 16, 4)
    const float* conv = (const float*)d_in[2];  // (N, 2)
    float* out = (float*)d_out;                 // (T, N)

    const int N = in_sizes[2] / 2;
    const int T = in_sizes[0] / (3 * N);

    const int grid = (N + 31) / 32;             // 32 chains/block, 1 wave/block
    hipLaunchKernelGGL(hbv_kernel, dim3(grid), dim3(64), 0, stream,
                       x, praw, conv, out, T, N);
}

// Round 4
// 544.611 us; speedup vs baseline: 1.2632x; 1.2632x over previous
//
#include <hip/hip_runtime.h>
#include <math.h>

#define NEARZERO 1e-5f
#define LENF 15

// ---- Geometry ---------------------------------------------------------------
// 4 n-chains per block -> 1000 blocks -> ~4 single-wave blocks per CU (one per
// SIMD). Rationale: rounds 1-2 fit a per-wave MLP cap (~60 outstanding 64B
// lines @ ~900cyc HBM latency -> ~4.3 B/cyc/wave). More miss-generating waves
// per CU is the only lever that raises aggregate fetch; VALU has headroom.
//
// Per 8-step batch: 8x global_load_lds(16B x 64 lanes = 1024B = one step's
// param slab) + 1x global_load_lds covering all 8 steps' forcing (24 lanes).
// Param slab swizzle (bank-conflict-free reads): dest 16B-beat b holds global
// beat b ^ ((b>>4)<<1) -- applied by pre-swizzling the per-lane SOURCE address
// (LDS dest stays linear as global_load_lds requires). Read side uses 4
// precomputed pointers with the XOR folded in; slot/param select via ds offset
// immediates -> zero per-read address VALU.
#define KB 8                                   // steps per batch
#define FORC_OFS (KB * 1024)                   // 8192: forcing slab in buffer
#define BUF_BYTES 8704                         // 8192 param + 384 forcing + pad
#define LDS_BYTES (2 * BUF_BYTES)              // 17408 B

// s_waitcnt immediates (gfx9: vmcnt[3:0]|[15:14], exp[6:4], lgkm[11:8])
#define WAIT_VMCNT_9  0x0F79                   // vmcnt(9): prologue, b0 resident
#define WAIT_VMCNT_17 0x4F71                   // vmcnt(17): 9 loads + 8 stores newer
#define WAIT_LGKM_0   0xC07F                   // lgkmcnt(0)

#define GPTR(p) ((const __attribute__((address_space(1))) void*)(p))
#define LPTR(p) ((__attribute__((address_space(3))) void*)(p))

// DPP quad_perm swaps within each quad of lanes (VALU, no LDS).
__device__ __forceinline__ float qswap1(float v) {
    return __int_as_float(__builtin_amdgcn_update_dpp(
        0, __float_as_int(v), 0xB1 /* quad_perm(1,0,3,2) */, 0xF, 0xF, true));
}
__device__ __forceinline__ float qswap2(float v) {
    return __int_as_float(__builtin_amdgcn_update_dpp(
        0, __float_as_int(v), 0x4E /* quad_perm(2,3,0,1) */, 0xF, 0xF, true));
}

// Fast x^y for x > 0 via v_log_f32/v_exp_f32 (both call sites clip to [0,1]
// and have provably positive arguments).
__device__ __forceinline__ float powpos(float x, float y) {
    return __builtin_amdgcn_exp2f(y * __builtin_amdgcn_logf(x));
}
__device__ __forceinline__ float rcpf(float x) { return __builtin_amdgcn_rcpf(x); }

// Stage one batch: 8 param loads + 1 forcing load = 9 vmem ops, ALWAYS issued
// (t clamped) so vmcnt arithmetic stays exact.
__device__ __forceinline__ void stage_batch(const char* __restrict__ praw_b,
                                            const char* __restrict__ x_b,
                                            char* smem, int buf, int t0,
                                            int T, int N, int n0, int lane,
                                            int perm16, int s3, int k16)
{
    char* bufp = smem + buf * BUF_BYTES;
#pragma unroll
    for (int s = 0; s < KB; ++s) {
        int ts = t0 + s;
        if (ts > T - 1) ts = T - 1;
        const char* gp = praw_b + (size_t)ts * ((size_t)N * 256) + (size_t)n0 * 256;
        __builtin_amdgcn_global_load_lds(GPTR(gp + perm16),
                                         LPTR(bufp + s * 1024), 16, 0, 0);
    }
    // Forcing for all 8 steps in one width-16 DMA: lane l (<24) covers step
    // l/3, 16B piece l%3 of the 48B span x[ts, n0:n0+4, 0:3]. Per-lane t clamp.
    if (lane < 24) {
        int ts = t0 + s3;
        if (ts > T - 1) ts = T - 1;
        const char* xg = x_b + (size_t)ts * ((size_t)N * 12) + (size_t)n0 * 12;
        __builtin_amdgcn_global_load_lds(GPTR(xg + k16),
                                         LPTR(bufp + FORC_OFS), 16, 0, 0);
    }
}

__device__ __forceinline__ float dostep(const float* __restrict__ pr, // 14 regs
                                        float P, float Ta, float PET,
                                        float& SNOWPACK, float& MELTWATER,
                                        float& SM, float& SUZ, float& SLZ)
{
    // TT is the only jump-discontinuous parameter (Ta >= TT): compute with
    // unfused mul+add to bit-match numpy's lo + raw*(hi-lo).
    const float BETA   = fmaf(pr[0],  5.0f,   1.0f);
    const float FC     = fmaf(pr[1],  950.0f, 50.0f);
    const float K0     = fmaf(pr[2],  0.85f,  0.05f);
    const float K1     = fmaf(pr[3],  0.49f,  0.01f);
    const float K2     = fmaf(pr[4],  0.199f, 0.001f);
    const float LP     = fmaf(pr[5],  0.8f,   0.2f);
    const float PERC   = pr[6] * 10.0f;
    const float UZL    = pr[7] * 100.0f;
    const float TT     = __fadd_rn(-2.5f, __fmul_rn(pr[8], 5.0f));
    const float CFMAX  = fmaf(pr[9],  9.5f,   0.5f);
    const float CFR    = pr[10] * 0.1f;
    const float CWH    = pr[11] * 0.2f;
    const float BETAET = fmaf(pr[12], 4.7f,   0.3f);
    const float C      = pr[13];

    const bool  wet  = (Ta >= TT);
    const float RAIN = wet ? P : 0.0f;
    const float SNOW = wet ? 0.0f : P;

    SNOWPACK += SNOW;
    const float melt = fminf(fmaxf(CFMAX * (Ta - TT), 0.0f), SNOWPACK);
    MELTWATER += melt;
    SNOWPACK = fmaxf(SNOWPACK - melt, NEARZERO);
    const float refreeze = fminf(fmaxf(CFR * CFMAX * (TT - Ta), 0.0f), MELTWATER);
    SNOWPACK += refreeze;
    MELTWATER = fmaxf(MELTWATER - refreeze, NEARZERO);
    const float tosoil = fmaxf(MELTWATER - CWH * SNOWPACK, 0.0f);
    MELTWATER = fmaxf(MELTWATER - tosoil, NEARZERO);

    const float rFC = rcpf(FC);
    float soil_wet = powpos(SM * rFC, BETA);
    soil_wet = fminf(fmaxf(soil_wet, 0.0f), 1.0f);
    const float recharge = (RAIN + tosoil) * soil_wet;
    SM = SM + RAIN + tosoil - recharge;
    const float excess = fmaxf(SM - FC, 0.0f);
    SM = fmaxf(SM - excess, NEARZERO);

    float evapfactor = powpos(SM * rcpf(LP * FC), BETAET);
    evapfactor = fminf(fmaxf(evapfactor, 0.0f), 1.0f);
    const float ETact = fminf(SM, PET * evapfactor);
    SM = fmaxf(SM - ETact, NEARZERO);

    const float capillary = fminf(SLZ, C * SLZ * (1.0f - fminf(SM * rFC, 1.0f)));
    SM += capillary;
    SLZ = fmaxf(SLZ - capillary, NEARZERO);

    SUZ = SUZ + recharge + excess;
    const float PERCa = fminf(SUZ, PERC);
    SUZ -= PERCa;
    const float Q0 = K0 * fmaxf(SUZ - UZL, 0.0f);
    SUZ -= Q0;
    const float Q1 = K1 * SUZ;
    SUZ -= Q1;
    SLZ += PERCa;
    const float Q2 = K2 * SLZ;
    SLZ -= Q2;
    return Q0 + Q1 + Q2;
}

// Log-domain gamma unit hydrograph (no OCML powf in the per-chain path).
__device__ __forceinline__ void make_uh(float craw0, float craw1, float* UH)
{
    const float a  = craw0 * 2.9f;
    const float b  = craw1 * 6.5f;
    const float aa = fmaxf(a, 0.0f) + 0.1f;
    const float th = fmaxf(b, 0.0f) + 0.5f;
    const float L2E = 1.4426950408889634f;
    const float c   = -lgammaf(aa) * L2E - aa * __builtin_amdgcn_logf(th);
    const float rthL = rcpf(th) * L2E;
    float wsum = 0.0f;
#pragma unroll
    for (int k = 0; k < LENF; ++k) {
        const float tt   = (float)k + 0.5f;
        const float l2tt = __builtin_log2f((float)k + 0.5f);   // constant-folded
        const float l2w  = fmaf(aa - 1.0f, l2tt, c) - tt * rthL;
        UH[k] = __builtin_amdgcn_exp2f(l2w);
        wsum += UH[k];
    }
    const float rs = rcpf(wsum);
#pragma unroll
    for (int k = 0; k < LENF; ++k) UH[k] *= rs;
}

__global__ void __launch_bounds__(64, 1)
hbv_kernel(const float* __restrict__ x,      // (T, N, 3)
           const float* __restrict__ praw,   // (T, N, 16, 4)
           const float* __restrict__ conv,   // (N, 2)
           float* __restrict__ out,          // (T, N)
           int T, int N)
{
    __shared__ __align__(16) char smem[LDS_BYTES];

    const int lane = threadIdx.x;
    int n0 = blockIdx.x * 4;                 // 4 n-chains per block
    if (n0 > N - 4) n0 = N - 4;              // safety clamp (dup writes benign)
    const int nl = (lane >> 2) & 3;          // chain within block (lanes 16-63
    const int m  = lane & 3;                 // duplicate lanes 0-15's work)
    const int n  = n0 + nl;
    // Stage-side source swizzle: dest beat l takes global beat l^((l>>4)<<1).
    const int perm16 = (lane ^ ((lane >> 3) & 6)) << 4;
    // Forcing-stage per-lane mapping (lanes < 24): step s3 = lane/3, 16B piece.
    const int s3  = lane / 3;
    const int k16 = (lane - 3 * s3) * 16;

    // --- Per-lane LDS read pointers (buffer 0) -------------------------------
    // Param i (bits b3 b2 b1 b0) lives at nl*256 + m*4 + 128*b3 + 64*(b2^q1)
    // + 32*(b1^q0) + 16*b0; slot s adds s*1024 (ds offset immediate).
    const int q0 = nl & 1, q1 = (nl >> 1) & 1;
    char* pp[4];
#pragma unroll
    for (int j = 0; j < 4; ++j) {
        const int d = 64 * (((j >> 1) & 1) ^ q1) + 32 * ((j & 1) ^ q0);
        pp[j] = smem + nl * 256 + m * 4 + d;
    }
    char* pf = smem + FORC_OFS + 12 * nl;

    // --- Unit hydrograph (identical across the 4 lanes of a quad) -----------
    float UH[LENF];
    make_uh(conv[2 * n], conv[2 * n + 1], UH);

    float acc[LENF - 1];
#pragma unroll
    for (int k = 0; k < LENF - 1; ++k) acc[k] = 0.0f;

    float S0 = 0.001f, S1 = 0.001f, S2 = 0.001f, S3v = 0.001f, S4 = 0.001f;

    const char* praw_b = (const char*)praw;
    const char* x_b    = (const char*)x;

    // Prologue: two batches in flight.
    stage_batch(praw_b, x_b, smem, 0, 0,  T, N, n0, lane, perm16, s3, k16);
    stage_batch(praw_b, x_b, smem, 1, KB, T, N, n0, lane, perm16, s3, k16);

    float pA[14], fA[3], pB[14], fB[3];      // ping-pong reg slabs

#define LOADSLOT(P, F, S)                                                     \
    {                                                                         \
        _Pragma("unroll")                                                     \
        for (int i = 0; i < 14; ++i) {                                        \
            const int j = 2 * ((i >> 2) & 1) + ((i >> 1) & 1);                \
            const int o = (S) * 1024 + 128 * (i >> 3) + 16 * (i & 1);         \
            P[i] = *(const float*)(pp[j] + o);                                \
        }                                                                     \
        _Pragma("unroll")                                                     \
        for (int k = 0; k < 3; ++k)                                           \
            F[k] = *(const float*)(pf + (S) * 48 + 4 * k);                    \
    }

#define STEPT(P, F, TIDX)                                                     \
    {                                                                         \
        float v = dostep(P, F[0], F[1], F[2], S0, S1, S2, S3v, S4);           \
        v += qswap1(v);                                                       \
        v += qswap2(v);                                                       \
        const float qq = v * 0.25f;                                           \
        const float e = fmaf(UH[0], qq, acc[0]);                              \
        _Pragma("unroll")                                                     \
        for (int k = 0; k < LENF - 2; ++k)                                    \
            acc[k] = fmaf(UH[k + 1], qq, acc[k + 1]);                         \
        acc[LENF - 2] = UH[LENF - 1] * qq;                                    \
        if ((lane & 0x33) == 0)  /* lanes 0,4,8,12: one store, no dups */     \
            out[(size_t)(TIDX) * N + n] = e;                                  \
    }

    // b0 resident (9 newer = b1's loads).
    __builtin_amdgcn_s_waitcnt(WAIT_VMCNT_9);
    __builtin_amdgcn_sched_barrier(0);

    int dl = BUF_BYTES;                      // ping-pong pointer delta
    int t = 0;
    const int nb = T / KB;                   // 45 full batches (360 steps)
    for (int bb = 0; bb < nb; ++bb) {
        // Batch bb resident: newer ops = iter bb-1's 8 stores + b(bb+1)'s 9
        // loads = 17. (No-op at bb=0 after the prologue wait.)
        __builtin_amdgcn_s_waitcnt(WAIT_VMCNT_17);
        __builtin_amdgcn_sched_barrier(0);

        // One-slot-ahead LDS->reg prefetch: ds_read latency hides under the
        // previous step's ~400cyc dependency chain.
        LOADSLOT(pA, fA, 0);
        LOADSLOT(pB, fB, 1);
        STEPT(pA, fA, t + 0);
        LOADSLOT(pA, fA, 2);
        STEPT(pB, fB, t + 1);
        LOADSLOT(pB, fB, 3);
        STEPT(pA, fA, t + 2);
        LOADSLOT(pA, fA, 4);
        STEPT(pB, fB, t + 3);
        LOADSLOT(pB, fB, 5);
        STEPT(pA, fA, t + 4);
        LOADSLOT(pA, fA, 6);
        STEPT(pB, fB, t + 5);
        LOADSLOT(pB, fB, 7);
        STEPT(pA, fA, t + 6);
        STEPT(pB, fB, t + 7);
        t += KB;

        // All ds_reads consumed; safe for DMA to overwrite this buffer.
        __builtin_amdgcn_s_waitcnt(WAIT_LGKM_0);
        __builtin_amdgcn_sched_barrier(0);
        stage_batch(praw_b, x_b, smem, bb & 1, (bb + 2) * KB, T, N, n0, lane,
                    perm16, s3, k16);
#pragma unroll
        for (int j = 0; j < 4; ++j) pp[j] += dl;
        pf += dl; dl = -dl;
    }

    // Tail: T=365 -> 5 guarded steps from buffer nb&1 (pointers already there).
    if (t < T) {
        __builtin_amdgcn_s_waitcnt(WAIT_VMCNT_17);
        __builtin_amdgcn_sched_barrier(0);
        for (int s = 0; s < KB && t < T; ++s, ++t) {
            LOADSLOT(pA, fA, s);
            STEPT(pA, fA, t);
        }
    }
#undef LOADSLOT
#undef STEPT
}

extern "C" void kernel_launch(void* const* d_in, const int* in_sizes, int n_in,
                              void* d_out, int out_size, void* d_ws, size_t ws_size,
                              hipStream_t stream)
{
    const float* x    = (const float*)d_in[0];  // (T, N, 3)
    const float* praw = (const float*)d_in[1];  // (T, N, 16, 4)
    const float* conv = (const float*)d_in[2];  // (N, 2)
    float* out = (float*)d_out;                 // (T, N)

    const int N = in_sizes[2] / 2;
    const int T = in_sizes[0] / (3 * N);

    const int grid = (N + 3) / 4;               // 4 chains/block, 1 wave/block
    hipLaunchKernelGGL(hbv_kernel, dim3(grid), dim3(64), 0, stream,
                       x, praw, conv, out, T, N);
}

// Round 5
// 502.545 us; speedup vs baseline: 1.3689x; 1.0837x over previous
//
#include <hip/hip_runtime.h>
#include <math.h>

#define NEARZERO 1e-5f
#define LENF 15

// ---- Geometry ---------------------------------------------------------------
// 16 n-chains per block (winning round-1 shape), 250 blocks, 1 wave/block.
// Total time = T x per-wave-step-cycles (T is serial; waves don't divide it),
// so everything here minimizes per-step cycles for one wave.
//
// Step slot: 4KB params (4 chunks x 1KB, 4 chains each) + 256B forcing
// (16B-stride per chain). Params staged by global_load_lds(width=16) with the
// per-lane SOURCE address XOR-swizzled (LDS dest linear, as the DMA requires):
// chunk-local 16B-beat b holds global beat b ^ ((b>>3)&6). Reads fold the
// inverse XOR into 4 precomputed per-lane word offsets; slot/param select is
// a compile-time immediate.
//
// CRITICAL vs rounds 0-4: ALL LDS reads go through direct indexing of a
// __shared__ float array with int offsets -- guaranteeing ds_read_b32
// codegen. Prior rounds carried generic char* pointers (arrays + loop-carried
// increments), the pattern where InferAddressSpaces fails and hipcc emits
// flat_load_dword (global-latency path, serialized ~60cyc/read -- fits all
// three measured configs: 17 reads->986cyc, 34->2143, 17->1230).
#define KB 7                                   // steps per batch
#define CHUNK_BYTES 1040                       // 1024 + 16 pad
#define CHUNK_WORDS 260
#define SLOT_PARAM_B (4 * CHUNK_BYTES)         // 4160 B
#define SLOT_PARAM_W (4 * CHUNK_WORDS)         // 1040 words
#define SLOT_BYTES (SLOT_PARAM_B + 256)        // 4416 B
#define SLOT_WORDS (SLOT_BYTES / 4)            // 1104 words
#define BUF_BYTES (KB * SLOT_BYTES)            // 30912 B
#define BUF_WORDS (KB * SLOT_WORDS)            // 7728 words
#define LDS_WORDS (2 * BUF_WORDS)              // 15456 words = 61824 B < 64KB

// s_waitcnt immediates (gfx9: vmcnt[3:0]|[15:14], exp[6:4], lgkm[11:8])
#define WAIT_VMCNT_35 0x8F73                   // vmcnt(35)
#define WAIT_LGKM_0   0xC07F                   // lgkmcnt(0)

#define GPTR(p) ((const __attribute__((address_space(1))) void*)(p))
#define LPTR(p) ((__attribute__((address_space(3))) void*)(p))

// DPP quad_perm swaps within each quad of lanes (VALU, no LDS).
__device__ __forceinline__ float qswap1(float v) {
    return __int_as_float(__builtin_amdgcn_update_dpp(
        0, __float_as_int(v), 0xB1 /* quad_perm(1,0,3,2) */, 0xF, 0xF, true));
}
__device__ __forceinline__ float qswap2(float v) {
    return __int_as_float(__builtin_amdgcn_update_dpp(
        0, __float_as_int(v), 0x4E /* quad_perm(2,3,0,1) */, 0xF, 0xF, true));
}

// Fast x^y for x > 0 via v_log_f32/v_exp_f32 (call sites clip to [0,1] and
// have provably positive arguments).
__device__ __forceinline__ float powpos(float x, float y) {
    return __builtin_amdgcn_exp2f(y * __builtin_amdgcn_logf(x));
}
__device__ __forceinline__ float rcpf(float x) { return __builtin_amdgcn_rcpf(x); }

// Stage one batch: per step 4 param DMAs (1KB each) + 1 forcing DMA = 35
// vmem ops per batch, ALWAYS issued (t clamped) so vmcnt stays exact.
__device__ __forceinline__ void stage_batch(const char* __restrict__ praw_b,
                                            const char* __restrict__ x_b,
                                            float* smemf, int buf, int t0,
                                            int T, int N, int n0, int lane,
                                            int perm16)
{
    char* bufp = (char*)smemf + buf * BUF_BYTES;
    for (int s = 0; s < KB; ++s) {
        int ts = t0 + s;
        if (ts > T - 1) ts = T - 1;
        const char* gp = praw_b + (size_t)ts * ((size_t)N * 256) + (size_t)n0 * 256;
        char* sp = bufp + s * SLOT_BYTES;
#pragma unroll
        for (int c = 0; c < 4; ++c) {
            __builtin_amdgcn_global_load_lds(GPTR(gp + c * 1024 + perm16),
                                             LPTR(sp + c * CHUNK_BYTES),
                                             16, 0, 0);
        }
        // Forcing: chain c's 3 words land at words 4c..4c+2 (16B stride, word
        // 4c+3 is pad). Lane l = 4c+k, k<3 active; width-4 DMA dest = word l.
        const char* xg = x_b + (size_t)ts * ((size_t)N * 12) + (size_t)n0 * 12;
        if ((lane & 3) != 3) {
            __builtin_amdgcn_global_load_lds(
                GPTR(xg + 4 * (3 * (lane >> 2) + (lane & 3))),
                LPTR(sp + SLOT_PARAM_B), 4, 0, 0);
        }
    }
}

__device__ __forceinline__ float dostep(const float* __restrict__ pr, // 14 regs
                                        float P, float Ta, float PET,
                                        float& SNOWPACK, float& MELTWATER,
                                        float& SM, float& SUZ, float& SLZ)
{
    // TT is the only jump-discontinuous parameter (Ta >= TT): compute with
    // unfused mul+add to bit-match numpy's lo + raw*(hi-lo).
    const float BETA   = fmaf(pr[0],  5.0f,   1.0f);
    const float FC     = fmaf(pr[1],  950.0f, 50.0f);
    const float K0     = fmaf(pr[2],  0.85f,  0.05f);
    const float K1     = fmaf(pr[3],  0.49f,  0.01f);
    const float K2     = fmaf(pr[4],  0.199f, 0.001f);
    const float LP     = fmaf(pr[5],  0.8f,   0.2f);
    const float PERC   = pr[6] * 10.0f;
    const float UZL    = pr[7] * 100.0f;
    const float TT     = __fadd_rn(-2.5f, __fmul_rn(pr[8], 5.0f));
    const float CFMAX  = fmaf(pr[9],  9.5f,   0.5f);
    const float CFR    = pr[10] * 0.1f;
    const float CWH    = pr[11] * 0.2f;
    const float BETAET = fmaf(pr[12], 4.7f,   0.3f);
    const float C      = pr[13];

    const bool  wet  = (Ta >= TT);
    const float RAIN = wet ? P : 0.0f;
    const float SNOW = wet ? 0.0f : P;

    SNOWPACK += SNOW;
    const float melt = fminf(fmaxf(CFMAX * (Ta - TT), 0.0f), SNOWPACK);
    MELTWATER += melt;
    SNOWPACK = fmaxf(SNOWPACK - melt, NEARZERO);
    const float refreeze = fminf(fmaxf(CFR * CFMAX * (TT - Ta), 0.0f), MELTWATER);
    SNOWPACK += refreeze;
    MELTWATER = fmaxf(MELTWATER - refreeze, NEARZERO);
    const float tosoil = fmaxf(MELTWATER - CWH * SNOWPACK, 0.0f);
    MELTWATER = fmaxf(MELTWATER - tosoil, NEARZERO);

    const float rFC = rcpf(FC);
    float soil_wet = powpos(SM * rFC, BETA);
    soil_wet = fminf(fmaxf(soil_wet, 0.0f), 1.0f);
    const float recharge = (RAIN + tosoil) * soil_wet;
    SM = SM + RAIN + tosoil - recharge;
    const float excess = fmaxf(SM - FC, 0.0f);
    SM = fmaxf(SM - excess, NEARZERO);

    float evapfactor = powpos(SM * rcpf(LP * FC), BETAET);
    evapfactor = fminf(fmaxf(evapfactor, 0.0f), 1.0f);
    const float ETact = fminf(SM, PET * evapfactor);
    SM = fmaxf(SM - ETact, NEARZERO);

    const float capillary = fminf(SLZ, C * SLZ * (1.0f - fminf(SM * rFC, 1.0f)));
    SM += capillary;
    SLZ = fmaxf(SLZ - capillary, NEARZERO);

    SUZ = SUZ + recharge + excess;
    const float PERCa = fminf(SUZ, PERC);
    SUZ -= PERCa;
    const float Q0 = K0 * fmaxf(SUZ - UZL, 0.0f);
    SUZ -= Q0;
    const float Q1 = K1 * SUZ;
    SUZ -= Q1;
    SLZ += PERCa;
    const float Q2 = K2 * SLZ;
    SLZ -= Q2;
    return Q0 + Q1 + Q2;
}

// Log-domain gamma unit hydrograph (no OCML powf).
__device__ __forceinline__ void make_uh(float craw0, float craw1, float* UH)
{
    const float a  = craw0 * 2.9f;
    const float b  = craw1 * 6.5f;
    const float aa = fmaxf(a, 0.0f) + 0.1f;
    const float th = fmaxf(b, 0.0f) + 0.5f;
    const float L2E = 1.4426950408889634f;
    const float c   = -lgammaf(aa) * L2E - aa * __builtin_amdgcn_logf(th);
    const float rthL = rcpf(th) * L2E;
    float wsum = 0.0f;
#pragma unroll
    for (int k = 0; k < LENF; ++k) {
        const float tt   = (float)k + 0.5f;
        const float l2tt = __builtin_log2f((float)k + 0.5f);   // constant-folded
        const float l2w  = fmaf(aa - 1.0f, l2tt, c) - tt * rthL;
        UH[k] = __builtin_amdgcn_exp2f(l2w);
        wsum += UH[k];
    }
    const float rs = rcpf(wsum);
#pragma unroll
    for (int k = 0; k < LENF; ++k) UH[k] *= rs;
}

__global__ void __launch_bounds__(64, 1)
hbv_kernel(const float* __restrict__ x,      // (T, N, 3)
           const float* __restrict__ praw,   // (T, N, 16, 4)
           const float* __restrict__ conv,   // (N, 2)
           float* __restrict__ out,          // (T, N)
           int T, int N)
{
    __shared__ __align__(16) float smemf[LDS_WORDS];

    const int lane = threadIdx.x;
    int n0 = blockIdx.x * 16;                // 16 n-chains per block
    if (n0 > N - 16) n0 = N - 16;            // guard (exact for N=4000)
    const int nl = lane >> 2;                // chain in block (0..15)
    const int m  = lane & 3;                 // ensemble member
    const int n  = n0 + nl;
    // Stage-side source swizzle: dest beat l takes global beat l^((l>>3)&6).
    const int perm16 = (lane ^ ((lane >> 3) & 6)) << 4;

    // --- Per-lane LDS read word-offsets (buffer 0) ---------------------------
    // Chunk a = nl>>2 holds chains 4a..4a+3 (local q = nl&3). Stored beat for
    // param i of chain q is i^2q, so param i (bits b3..b0) lives at word:
    //   a*260 + q*64 + m + 32*b3 + 16*(b2^q1) + 8*(b1^q0) + 4*b0
    // pb[j], j = 2*b2 + b1, pre-folds the XOR; b3/b0/slot are immediates.
    const int a  = nl >> 2;
    const int q  = nl & 3;
    const int q0 = q & 1, q1 = (q >> 1) & 1;
    int pb[4];
#pragma unroll
    for (int j = 0; j < 4; ++j)
        pb[j] = a * CHUNK_WORDS + q * 64 + m
              + 16 * (((j >> 1) & 1) ^ q1) + 8 * ((j & 1) ^ q0);
    int fb = SLOT_PARAM_W + 4 * nl;

    // --- Unit hydrograph (identical across the 4 lanes of a quad) -----------
    float UH[LENF];
    make_uh(conv[2 * n], conv[2 * n + 1], UH);

    float acc[LENF - 1];
#pragma unroll
    for (int k = 0; k < LENF - 1; ++k) acc[k] = 0.0f;

    float S0 = 0.001f, S1 = 0.001f, S2 = 0.001f, S3v = 0.001f, S4 = 0.001f;

    const char* praw_b = (const char*)praw;
    const char* x_b    = (const char*)x;

    // Prologue: two batches in flight (70 loads outstanding).
    stage_batch(praw_b, x_b, smemf, 0, 0,  T, N, n0, lane, perm16);
    stage_batch(praw_b, x_b, smemf, 1, KB, T, N, n0, lane, perm16);

    float pA[14], fA[3], pB[14], fB[3];      // ping-pong reg slabs

// All reads are direct __shared__ indexing with int offsets -> ds_read_b32
// with immediate slot/param offsets (byte offs < 31KB, within 16-bit imm).
#define LOADSLOT(P, F, S)                                                     \
    {                                                                         \
        _Pragma("unroll")                                                     \
        for (int i = 0; i < 14; ++i) {                                        \
            const int j = 2 * ((i >> 2) & 1) + ((i >> 1) & 1);                \
            P[i] = smemf[pb[j] + (S) * SLOT_WORDS + 32 * (i >> 3) + 4 * (i & 1)]; \
        }                                                                     \
        _Pragma("unroll")                                                     \
        for (int k = 0; k < 3; ++k)                                           \
            F[k] = smemf[fb + (S) * SLOT_WORDS + k];                          \
    }

#define STEPT(P, F, TIDX)                                                     \
    {                                                                         \
        float v = dostep(P, F[0], F[1], F[2], S0, S1, S2, S3v, S4);           \
        v += qswap1(v);                                                       \
        v += qswap2(v);                                                       \
        const float qq = v * 0.25f;                                           \
        const float e = fmaf(UH[0], qq, acc[0]);                              \
        _Pragma("unroll")                                                     \
        for (int k = 0; k < LENF - 2; ++k)                                    \
            acc[k] = fmaf(UH[k + 1], qq, acc[k + 1]);                         \
        acc[LENF - 2] = UH[LENF - 1] * qq;                                    \
        if (m == 0) out[(size_t)(TIDX) * N + n] = e;                          \
    }

    int dw = BUF_WORDS;                      // ping-pong word delta
    int t = 0;
    const int nb = T / KB;                   // 52 full batches (364 steps)
    for (int bb = 0; bb < nb; ++bb) {
        // Batch bb resident: outstanding = loads bb (35) + stores bb-1 (7)
        // + loads bb+1 (35); wait <=35 drains loads bb (and the stores).
        __builtin_amdgcn_s_waitcnt(WAIT_VMCNT_35);
        __builtin_amdgcn_sched_barrier(0);

        // One-slot-ahead LDS->reg prefetch; ds_read latency hides under the
        // previous step's dependency chain.
        LOADSLOT(pA, fA, 0);
        LOADSLOT(pB, fB, 1);
        STEPT(pA, fA, t + 0);
        LOADSLOT(pA, fA, 2);
        STEPT(pB, fB, t + 1);
        LOADSLOT(pB, fB, 3);
        STEPT(pA, fA, t + 2);
        LOADSLOT(pA, fA, 4);
        STEPT(pB, fB, t + 3);
        LOADSLOT(pB, fB, 5);
        STEPT(pA, fA, t + 4);
        LOADSLOT(pA, fA, 6);
        STEPT(pB, fB, t + 5);
        STEPT(pA, fA, t + 6);
        t += KB;

        // All ds_reads consumed (data deps); DMA may overwrite this buffer.
        __builtin_amdgcn_s_waitcnt(WAIT_LGKM_0);
        __builtin_amdgcn_sched_barrier(0);
        stage_batch(praw_b, x_b, smemf, bb & 1, (bb + 2) * KB, T, N, n0, lane,
                    perm16);
#pragma unroll
        for (int j = 0; j < 4; ++j) pb[j] += dw;
        fb += dw; dw = -dw;
    }

    // Tail: T=365 -> exactly 1 step; offsets already point at buffer nb&1.
    if (t < T) {
        __builtin_amdgcn_s_waitcnt(WAIT_VMCNT_35);
        __builtin_amdgcn_sched_barrier(0);
        for (int s = 0; s < KB && t < T; ++s, ++t) {
            LOADSLOT(pA, fA, s);
            STEPT(pA, fA, t);
        }
    }
#undef LOADSLOT
#undef STEPT
}

extern "C" void kernel_launch(void* const* d_in, const int* in_sizes, int n_in,
                              void* d_out, int out_size, void* d_ws, size_t ws_size,
                              hipStream_t stream)
{
    const float* x    = (const float*)d_in[0];  // (T, N, 3)
    const float* praw = (const float*)d_in[1];  // (T, N, 16, 4)
    const float* conv = (const float*)d_in[2];  // (N, 2)
    float* out = (float*)d_out;                 // (T, N)

    const int N = in_sizes[2] / 2;
    const int T = in_sizes[0] / (3 * N);

    const int grid = (N + 15) / 16;             // 16 chains/block, 1 wave/block
    hipLaunchKernelGGL(hbv_kernel, dim3(grid), dim3(64), 0, stream,
                       x, praw, conv, out, T, N);
}